// Round 6
// baseline (18.501 us; speedup 1.0000x reference)
//
#include <hip/hip_runtime.h>

// MoE: E=8 experts, Linear(1->32)+ReLU+Linear(32->1), softmax(-sq_err over 4
// context points) weighting.
//
// Round-6 = round-3 structure (4096 blocks, thread=(b,e), register knot
// table, 8-lane-group softmax) with precision+op trims:
//  - alpha/beta folded into accumulator INIT (a = fma(alpha,x,beta)), not a
//    pseudo-knot at -16: saves ~12 insts and recovers the cancellation loss
//    (round-2 absmax 9.8e-4 vs round-3 3.9e-3).
//  - wo/s via v_rcp_f32 (rel err ~1e-7) instead of IEEE divide.
//  - s_setprio(1) around the knot loop (waves are barrier-free, different
//    phases -> T5-favorable regime).
// Measured decomposition (rounds 4/5): knot loop ~5.6 us at ~80% of the
// 4.4 us fp32-VALU issue floor; ~9.5 us fixed (graph replay + ramp).

constexpr int E = 8;
constexpr int H = 32;
constexpr int STRIDE = 34;  // float2 per expert row (padded: 272 B rows)

__global__ __launch_bounds__(256) void moe_kernel(
    const float* __restrict__ ctx,   // [B, 8]
    const float* __restrict__ inp,   // [B, 1]
    const float* __restrict__ W1,    // [E, 1, H]
    const float* __restrict__ b1,    // [E, H]
    const float* __restrict__ W2,    // [E, H, 1]
    const float* __restrict__ b2,    // [E, 1]
    float* __restrict__ out,         // [B, 1]
    int B)
{
    __shared__ __align__(16) float2 crs[E * STRIDE];  // 2176 B

    const int t = threadIdx.x;
    {
        // prologue: one thread per (e,h). w2*relu(w1 x + b1) =
        // (0.5 w2 w1) x + (0.5 w2 b1) + (0.5 w2 |w1|) |x + b1/w1|
        const int e = t >> 5;
        const int h = t & 31;
        const float w1  = W1[e * H + h];
        const float b1v = b1[e * H + h];
        const float w2  = W2[e * H + h];
        const float aw  = fabsf(w1);
        const bool tiny = aw < 1e-20f;
        const float c = tiny ? 0.f : 0.5f * w2 * aw;
        const float r = tiny ? 0.f : (-b1v / w1);
        float pa = tiny ? 0.f : 0.5f * w2 * w1;
        float pb = tiny ? (w2 * fmaxf(b1v, 0.f)) : (0.5f * w2 * b1v);

        crs[e * STRIDE + h] = make_float2(c, r);

        #pragma unroll
        for (int m = 1; m < 32; m <<= 1) {
            pa += __shfl_xor(pa, m);
            pb += __shfl_xor(pb, m);
        }
        if (h == 0) {
            crs[e * STRIDE + 32] = make_float2(pa, pb + b2[e]);  // (alpha, beta)
        }
    }
    __syncthreads();

    const int g = blockIdx.x * 256 + t;
    const int b = g >> 3;
    const int e = g & 7;
    if (b >= B) return;

    const float4 c0 = reinterpret_cast<const float4*>(ctx)[b * 2 + 0];
    const float4 c1 = reinterpret_cast<const float4*>(ctx)[b * 2 + 1];
    const float x4 = inp[b];

    // expert table: 16x ds_read_b128 (knots) + 1x ds_read_b64 (alpha,beta);
    // row base byte e*272 -> bank 4e, disjoint per lane-group, bcast across.
    float4 crq[16];
    const float4* __restrict__ rowp =
        reinterpret_cast<const float4*>(&crs[e * STRIDE]);
    #pragma unroll
    for (int i = 0; i < 16; ++i) crq[i] = rowp[i];
    const float2 ab = crs[e * STRIDE + 32];
    const float alpha = ab.x, beta = ab.y;

    float a0 = fmaf(alpha, c0.x, beta);
    float a1 = fmaf(alpha, c0.z, beta);
    float a2 = fmaf(alpha, c1.x, beta);
    float a3 = fmaf(alpha, c1.z, beta);
    float a4 = fmaf(alpha, x4,  beta);

    __builtin_amdgcn_s_setprio(1);
    #pragma unroll
    for (int i = 0; i < 16; ++i) {
        {
            const float c = crq[i].x, r = crq[i].y;
            a0 = fmaf(c, fabsf(c0.x - r), a0);
            a1 = fmaf(c, fabsf(c0.z - r), a1);
            a2 = fmaf(c, fabsf(c1.x - r), a2);
            a3 = fmaf(c, fabsf(c1.z - r), a3);
            a4 = fmaf(c, fabsf(x4  - r), a4);
        }
        {
            const float c = crq[i].z, r = crq[i].w;
            a0 = fmaf(c, fabsf(c0.x - r), a0);
            a1 = fmaf(c, fabsf(c0.z - r), a1);
            a2 = fmaf(c, fabsf(c1.x - r), a2);
            a3 = fmaf(c, fabsf(c1.z - r), a3);
            a4 = fmaf(c, fabsf(x4  - r), a4);
        }
    }
    __builtin_amdgcn_s_setprio(0);

    const float p0 = a0 - c0.y;
    const float p1 = a1 - c0.w;
    const float p2 = a2 - c1.y;
    const float p3 = a3 - c1.w;
    const float err = fmaf(p0, p0, fmaf(p1, p1, fmaf(p2, p2, p3 * p3)));
    const float oe  = a4;

    // softmax(-err) over the 8 experts in this 8-lane group
    float m = err;
    m = fminf(m, __shfl_xor(m, 1));
    m = fminf(m, __shfl_xor(m, 2));
    m = fminf(m, __shfl_xor(m, 4));
    const float w = __expf(m - err);
    float s  = w;
    float wo = w * oe;
    s  += __shfl_xor(s, 1);  wo += __shfl_xor(wo, 1);
    s  += __shfl_xor(s, 2);  wo += __shfl_xor(wo, 2);
    s  += __shfl_xor(s, 4);  wo += __shfl_xor(wo, 4);

    if (e == 0) out[b] = wo * __builtin_amdgcn_rcpf(s);
}

extern "C" void kernel_launch(void* const* d_in, const int* in_sizes, int n_in,
                              void* d_out, int out_size, void* d_ws, size_t ws_size,
                              hipStream_t stream) {
    const float* ctx = (const float*)d_in[0];
    const float* inp = (const float*)d_in[1];
    const float* W1  = (const float*)d_in[2];
    const float* b1  = (const float*)d_in[3];
    const float* W2  = (const float*)d_in[4];
    const float* b2  = (const float*)d_in[5];
    float* out = (float*)d_out;

    const int B = in_sizes[1];  // input is [B,1]
    const long long total = (long long)B * 8;
    const int threads = 256;
    const int blocks = (int)((total + threads - 1) / threads);
    hipLaunchKernelGGL(moe_kernel, dim3(blocks), dim3(threads), 0, stream,
                       ctx, inp, W1, b1, W2, b2, out, B);
}

// Round 7
// 14.720 us; speedup vs baseline: 1.2568x; 1.2568x over previous
//
#include <hip/hip_runtime.h>

// MoE: E=8 experts, Linear(1->32)+ReLU+Linear(32->1), softmax(-sq_err over 4
// context points) weighting.
//
// Round-7 = round-6 minus s_setprio (the regression: all-wave prio-1 has
// nothing to arbitrate, and the intrinsic fences the compiler's pipelining
// of the 16 ds_read_b128 preloads into the loop head). Keeps the free trims:
//  - alpha/beta folded into accumulator init (saves the entry-32 eval)
//  - wo/s via v_rcp_f32
// Measured decomposition (rounds 4/5): knot loop ~5.6 us (~80% of its
// 4.4 us fp32-VALU issue floor) + ~9.5 us fixed (graph replay + ramp),
// invariant across 3 kernel structures and 2 grid configs.

constexpr int E = 8;
constexpr int H = 32;
constexpr int STRIDE = 34;  // float2 per expert row (padded: 272 B rows)

__global__ __launch_bounds__(256) void moe_kernel(
    const float* __restrict__ ctx,   // [B, 8]
    const float* __restrict__ inp,   // [B, 1]
    const float* __restrict__ W1,    // [E, 1, H]
    const float* __restrict__ b1,    // [E, H]
    const float* __restrict__ W2,    // [E, H, 1]
    const float* __restrict__ b2,    // [E, 1]
    float* __restrict__ out,         // [B, 1]
    int B)
{
    __shared__ __align__(16) float2 crs[E * STRIDE];  // 2176 B

    const int t = threadIdx.x;
    {
        // prologue: one thread per (e,h). w2*relu(w1 x + b1) =
        // (0.5 w2 w1) x + (0.5 w2 b1) + (0.5 w2 |w1|) |x + b1/w1|
        const int e = t >> 5;
        const int h = t & 31;
        const float w1  = W1[e * H + h];
        const float b1v = b1[e * H + h];
        const float w2  = W2[e * H + h];
        const float aw  = fabsf(w1);
        const bool tiny = aw < 1e-20f;
        const float c = tiny ? 0.f : 0.5f * w2 * aw;
        const float r = tiny ? 0.f : (-b1v / w1);
        float pa = tiny ? 0.f : 0.5f * w2 * w1;
        float pb = tiny ? (w2 * fmaxf(b1v, 0.f)) : (0.5f * w2 * b1v);

        crs[e * STRIDE + h] = make_float2(c, r);

        #pragma unroll
        for (int m = 1; m < 32; m <<= 1) {
            pa += __shfl_xor(pa, m);
            pb += __shfl_xor(pb, m);
        }
        if (h == 0) {
            crs[e * STRIDE + 32] = make_float2(pa, pb + b2[e]);  // (alpha, beta)
        }
    }
    __syncthreads();

    const int g = blockIdx.x * 256 + t;
    const int b = g >> 3;
    const int e = g & 7;
    if (b >= B) return;

    const float4 c0 = reinterpret_cast<const float4*>(ctx)[b * 2 + 0];
    const float4 c1 = reinterpret_cast<const float4*>(ctx)[b * 2 + 1];
    const float x4 = inp[b];

    // expert table: 16x ds_read_b128 (knots) + 1x ds_read_b64 (alpha,beta);
    // row base byte e*272 -> bank 4e, disjoint per lane-group, bcast across.
    float4 crq[16];
    const float4* __restrict__ rowp =
        reinterpret_cast<const float4*>(&crs[e * STRIDE]);
    #pragma unroll
    for (int i = 0; i < 16; ++i) crq[i] = rowp[i];
    const float2 ab = crs[e * STRIDE + 32];
    const float alpha = ab.x, beta = ab.y;

    float a0 = fmaf(alpha, c0.x, beta);
    float a1 = fmaf(alpha, c0.z, beta);
    float a2 = fmaf(alpha, c1.x, beta);
    float a3 = fmaf(alpha, c1.z, beta);
    float a4 = fmaf(alpha, x4,  beta);

    #pragma unroll
    for (int i = 0; i < 16; ++i) {
        {
            const float c = crq[i].x, r = crq[i].y;
            a0 = fmaf(c, fabsf(c0.x - r), a0);
            a1 = fmaf(c, fabsf(c0.z - r), a1);
            a2 = fmaf(c, fabsf(c1.x - r), a2);
            a3 = fmaf(c, fabsf(c1.z - r), a3);
            a4 = fmaf(c, fabsf(x4  - r), a4);
        }
        {
            const float c = crq[i].z, r = crq[i].w;
            a0 = fmaf(c, fabsf(c0.x - r), a0);
            a1 = fmaf(c, fabsf(c0.z - r), a1);
            a2 = fmaf(c, fabsf(c1.x - r), a2);
            a3 = fmaf(c, fabsf(c1.z - r), a3);
            a4 = fmaf(c, fabsf(x4  - r), a4);
        }
    }

    const float p0 = a0 - c0.y;
    const float p1 = a1 - c0.w;
    const float p2 = a2 - c1.y;
    const float p3 = a3 - c1.w;
    const float err = fmaf(p0, p0, fmaf(p1, p1, fmaf(p2, p2, p3 * p3)));
    const float oe  = a4;

    // softmax(-err) over the 8 experts in this 8-lane group
    float m = err;
    m = fminf(m, __shfl_xor(m, 1));
    m = fminf(m, __shfl_xor(m, 2));
    m = fminf(m, __shfl_xor(m, 4));
    const float w = __expf(m - err);
    float s  = w;
    float wo = w * oe;
    s  += __shfl_xor(s, 1);  wo += __shfl_xor(wo, 1);
    s  += __shfl_xor(s, 2);  wo += __shfl_xor(wo, 2);
    s  += __shfl_xor(s, 4);  wo += __shfl_xor(wo, 4);

    if (e == 0) out[b] = wo * __builtin_amdgcn_rcpf(s);
}

extern "C" void kernel_launch(void* const* d_in, const int* in_sizes, int n_in,
                              void* d_out, int out_size, void* d_ws, size_t ws_size,
                              hipStream_t stream) {
    const float* ctx = (const float*)d_in[0];
    const float* inp = (const float*)d_in[1];
    const float* W1  = (const float*)d_in[2];
    const float* b1  = (const float*)d_in[3];
    const float* W2  = (const float*)d_in[4];
    const float* b2  = (const float*)d_in[5];
    float* out = (float*)d_out;

    const int B = in_sizes[1];  // input is [B,1]
    const long long total = (long long)B * 8;
    const int threads = 256;
    const int blocks = (int)((total + threads - 1) / threads);
    hipLaunchKernelGGL(moe_kernel, dim3(blocks), dim3(threads), 0, stream,
                       ctx, inp, W1, b1, W2, b2, out, B);
}